// Round 1
// baseline (991.266 us; speedup 1.0000x reference)
//
#include <hip/hip_runtime.h>
#include <hip/hip_bf16.h>

#define DD 128

typedef __attribute__((ext_vector_type(8))) short bfrag8;
typedef __attribute__((ext_vector_type(4))) float f32x4;

__device__ __forceinline__ float bf16lo(unsigned int u) {
    union { unsigned int i; float f; } c; c.i = u << 16; return c.f;
}
__device__ __forceinline__ float bf16hi(unsigned int u) {
    union { unsigned int i; float f; } c; c.i = u & 0xffff0000u; return c.f;
}
__device__ __forceinline__ unsigned short f2bf(float f) {
    union { float f; unsigned int i; } c; c.f = f;
    unsigned int x = c.i;
    unsigned int r = (x + 0x7fffu + ((x >> 16) & 1u)) >> 16;  // RNE
    return (unsigned short)r;
}

// ---------------- CSR build ----------------
__global__ void k_hist(const int* __restrict__ dst, int* __restrict__ deg, int E) {
    int i = blockIdx.x * blockDim.x + threadIdx.x;
    if (i < E) atomicAdd(&deg[dst[i]], 1);
}

__global__ void k_scan1(const int* __restrict__ deg, int* __restrict__ partials, int Nn) {
    __shared__ int s[1024];
    int i = blockIdx.x * 1024 + threadIdx.x;
    s[threadIdx.x] = (i < Nn) ? deg[i] : 0;
    __syncthreads();
    for (int off = 512; off > 0; off >>= 1) {
        if (threadIdx.x < off) s[threadIdx.x] += s[threadIdx.x + off];
        __syncthreads();
    }
    if (threadIdx.x == 0) partials[blockIdx.x] = s[0];
}

__global__ void k_scan2(const int* __restrict__ partials, int* __restrict__ pscan, int nb) {
    if (threadIdx.x == 0) {
        int acc = 0;
        for (int i = 0; i < nb; i++) { pscan[i] = acc; acc += partials[i]; }
    }
}

__global__ void k_scan3(const int* __restrict__ deg, const int* __restrict__ pscan,
                        int* __restrict__ row_start, int Nn, int E) {
    __shared__ int s[1024];
    int i = blockIdx.x * 1024 + threadIdx.x;
    int v = (i < Nn) ? deg[i] : 0;
    s[threadIdx.x] = v;
    __syncthreads();
    for (int off = 1; off < 1024; off <<= 1) {
        int t = (threadIdx.x >= off) ? s[threadIdx.x - off] : 0;
        __syncthreads();
        s[threadIdx.x] += t;
        __syncthreads();
    }
    if (i < Nn) row_start[i] = pscan[blockIdx.x] + s[threadIdx.x] - v;
    if (blockIdx.x == 0 && threadIdx.x == 0) row_start[Nn] = E;
}

__global__ void k_scatter(const int* __restrict__ src, const int* __restrict__ dst,
                          const int* __restrict__ row_start, int* __restrict__ cursor,
                          int* __restrict__ csr, int E) {
    int i = blockIdx.x * blockDim.x + threadIdx.x;
    if (i < E) {
        int d = dst[i];
        int pos = row_start[d] + atomicAdd(&cursor[d], 1);
        csr[pos] = src[i];
    }
}

// ---------------- converts ----------------
// features -> out[0] (fp32) + hb (bf16 packed)
__global__ void k_cvt_feat(const float* __restrict__ f, float* __restrict__ out0,
                           unsigned int* __restrict__ hb, int total4) {
    int i = blockIdx.x * blockDim.x + threadIdx.x;
    if (i >= total4) return;
    float4 v = ((const float4*)f)[i];
    ((float4*)out0)[i] = v;
    unsigned int lo = (unsigned int)f2bf(v.x) | ((unsigned int)f2bf(v.y) << 16);
    unsigned int hi = (unsigned int)f2bf(v.z) | ((unsigned int)f2bf(v.w) << 16);
    ((uint2*)hb)[i] = make_uint2(lo, hi);
}

// W[l][k][n] fp32 -> Wt[l][n][k] bf16
__global__ void k_cvtW(const float* __restrict__ W, unsigned short* __restrict__ Wt, int total) {
    int i = blockIdx.x * blockDim.x + threadIdx.x;
    if (i >= total) return;
    int l = i >> 14;
    int r = i & 16383;
    int k = r >> 7, n = r & 127;
    Wt[(l << 14) + n * 128 + k] = f2bf(W[i]);
}

// ---------------- gather: z = (1+eps)*h + sum_{u in N(v)} h_u  (bf16 in, bf16 out) ----------------
__global__ void k_gather(const unsigned int* __restrict__ hb, const int* __restrict__ row_start,
                         const int* __restrict__ csr, const float* __restrict__ eps, int layer,
                         unsigned int* __restrict__ zb, int Nn) {
    int wv = threadIdx.x >> 6, lane = threadIdx.x & 63;
    int v = blockIdx.x * 4 + wv;
    if (v >= Nn) return;
    float e1 = 1.0f + eps[layer];
    unsigned int hs = hb[v * 64 + lane];
    float ax = e1 * bf16lo(hs);
    float ay = e1 * bf16hi(hs);
    int beg = row_start[v], end = row_start[v + 1];
    int e = beg;
    for (; e + 3 < end; e += 4) {
        int u0 = csr[e], u1 = csr[e + 1], u2 = csr[e + 2], u3 = csr[e + 3];
        unsigned int h0 = hb[u0 * 64 + lane];
        unsigned int h1 = hb[u1 * 64 + lane];
        unsigned int h2 = hb[u2 * 64 + lane];
        unsigned int h3 = hb[u3 * 64 + lane];
        ax += bf16lo(h0) + bf16lo(h1) + bf16lo(h2) + bf16lo(h3);
        ay += bf16hi(h0) + bf16hi(h1) + bf16hi(h2) + bf16hi(h3);
    }
    for (; e < end; e++) {
        unsigned int hu = hb[csr[e] * 64 + lane];
        ax += bf16lo(hu); ay += bf16hi(hu);
    }
    zb[v * 64 + lane] = (unsigned int)f2bf(ax) | ((unsigned int)f2bf(ay) << 16);
}

// ---------------- GEMM: y = zb @ Wt^T + b, fused BN1 column stats ----------------
// block = 256 thr (4 waves), tile 64 rows x 128 cols, K=128 fully staged.
__launch_bounds__(256)
__global__ void k_gemm(const unsigned short* __restrict__ zb, const unsigned short* __restrict__ Wt,
                       const float* __restrict__ bias, int layer, float* __restrict__ y,
                       float* __restrict__ s1sum, float* __restrict__ s1sq, int Nn) {
    __shared__ unsigned short Al[64 * 136];
    __shared__ unsigned short Bl[128 * 136];
    int tid = threadIdx.x;
    int m0 = blockIdx.x * 64;
    const unsigned short* Wl = Wt + (layer << 14);
    // stage W (128 rows x 16 chunks of 8 ushorts)
    #pragma unroll
    for (int p = 0; p < 8; p++) {
        int slot = p * 256 + tid;
        int n = slot >> 4, c = slot & 15;
        *(uint4*)&Bl[n * 136 + c * 8] = *(const uint4*)&Wl[n * 128 + c * 8];
    }
    // stage A (64 rows x 16 chunks)
    #pragma unroll
    for (int p = 0; p < 4; p++) {
        int slot = p * 256 + tid;
        int r = slot >> 4, c = slot & 15;
        int grow = m0 + r;
        uint4 val = make_uint4(0, 0, 0, 0);
        if (grow < Nn) val = *(const uint4*)&zb[(size_t)grow * 128 + c * 8];
        *(uint4*)&Al[r * 136 + c * 8] = val;
    }
    __syncthreads();

    int lane = tid & 63, wv = tid >> 6;
    int tcol = lane & 15, quad = lane >> 4;
    f32x4 acc[4][2];
    #pragma unroll
    for (int a = 0; a < 4; a++)
        #pragma unroll
        for (int b2 = 0; b2 < 2; b2++) acc[a][b2] = (f32x4){0.f, 0.f, 0.f, 0.f};

    #pragma unroll
    for (int kk = 0; kk < 128; kk += 32) {
        int kb = kk + quad * 8;
        bfrag8 af[4], bf[2];
        #pragma unroll
        for (int mt = 0; mt < 4; mt++)
            af[mt] = *(const bfrag8*)&Al[(16 * mt + tcol) * 136 + kb];
        #pragma unroll
        for (int nt = 0; nt < 2; nt++)
            bf[nt] = *(const bfrag8*)&Bl[(32 * wv + 16 * nt + tcol) * 136 + kb];
        #pragma unroll
        for (int mt = 0; mt < 4; mt++)
            #pragma unroll
            for (int nt = 0; nt < 2; nt++)
                acc[mt][nt] = __builtin_amdgcn_mfma_f32_16x16x32_bf16(af[mt], bf[nt], acc[mt][nt], 0, 0, 0);
    }

    // epilogue: bias, store y, BN1 partial stats
    #pragma unroll
    for (int nt = 0; nt < 2; nt++) {
        int col = 32 * wv + 16 * nt + tcol;
        float bcol = bias[layer * 128 + col];
        float psum = 0.f, psq = 0.f;
        #pragma unroll
        for (int mt = 0; mt < 4; mt++) {
            #pragma unroll
            for (int r = 0; r < 4; r++) {
                int row = m0 + 16 * mt + quad * 4 + r;
                float val = acc[mt][nt][r] + bcol;
                if (row < Nn) {
                    y[(size_t)row * 128 + col] = val;
                    psum += val;
                    psq += val * val;
                }
            }
        }
        psum += __shfl_xor(psum, 16); psq += __shfl_xor(psq, 16);
        psum += __shfl_xor(psum, 32); psq += __shfl_xor(psq, 32);
        if (lane < 16) {
            atomicAdd(&s1sum[col], psum);
            atomicAdd(&s1sq[col], psq);
        }
    }
}

// ---------------- BN finalize: scale/shift; resets accumulators for next use ----------------
__global__ void k_fin(float* __restrict__ sum, float* __restrict__ sq,
                      const float* __restrict__ gamma, const float* __restrict__ beta, int layer,
                      float* __restrict__ sc, float* __restrict__ sh, float invN) {
    int c = threadIdx.x;
    float m = sum[c] * invN;
    float var = sq[c] * invN - m * m;
    float rstd = rsqrtf(var + 1e-5f);
    float s = gamma[layer * 128 + c] * rstd;
    sc[c] = s;
    sh[c] = beta[layer * 128 + c] - m * s;
    sum[c] = 0.f;
    sq[c] = 0.f;
}

// ---------------- BN2 stats over relu(affine1(y)) ----------------
__global__ void k_stats2(const float* __restrict__ y, const float* __restrict__ s1,
                         const float* __restrict__ sh1, float* __restrict__ s2sum,
                         float* __restrict__ s2sq, int Nn) {
    int c = threadIdx.x & 127;
    int r0 = blockIdx.x * 2 + (threadIdx.x >> 7);
    float sc = s1[c], sh = sh1[c];
    float sum = 0.f, sq = 0.f;
    int stride = gridDim.x * 2;
    for (int r = r0; r < Nn; r += stride) {
        float t = fmaxf(y[(size_t)r * 128 + c] * sc + sh, 0.f);
        sum += t;
        sq += t * t;
    }
    atomicAdd(&s2sum[c], sum);
    atomicAdd(&s2sq[c], sq);
}

// ---------------- apply: h = relu(aff2(relu(aff1(y)))) in-place into out slab + bf16 copy ----------------
__global__ void k_apply(float* __restrict__ y, const float* __restrict__ s1,
                        const float* __restrict__ sh1, const float* __restrict__ s2,
                        const float* __restrict__ sh2, unsigned int* __restrict__ hb, int total4) {
    int i = blockIdx.x * blockDim.x + threadIdx.x;
    if (i >= total4) return;
    int c = (i * 4) & 127;
    float4 v = ((float4*)y)[i];
    float t0 = fmaxf(v.x * s1[c] + sh1[c], 0.f);
    float t1 = fmaxf(v.y * s1[c + 1] + sh1[c + 1], 0.f);
    float t2 = fmaxf(v.z * s1[c + 2] + sh1[c + 2], 0.f);
    float t3 = fmaxf(v.w * s1[c + 3] + sh1[c + 3], 0.f);
    float o0 = fmaxf(t0 * s2[c] + sh2[c], 0.f);
    float o1 = fmaxf(t1 * s2[c + 1] + sh2[c + 1], 0.f);
    float o2 = fmaxf(t2 * s2[c + 2] + sh2[c + 2], 0.f);
    float o3 = fmaxf(t3 * s2[c + 3] + sh2[c + 3], 0.f);
    ((float4*)y)[i] = make_float4(o0, o1, o2, o3);
    unsigned int lo = (unsigned int)f2bf(o0) | ((unsigned int)f2bf(o1) << 16);
    unsigned int hi = (unsigned int)f2bf(o2) | ((unsigned int)f2bf(o3) << 16);
    ((uint2*)hb)[i] = make_uint2(lo, hi);
}

extern "C" void kernel_launch(void* const* d_in, const int* in_sizes, int n_in,
                              void* d_out, int out_size, void* d_ws, size_t ws_size,
                              hipStream_t stream) {
    const float* features = (const float*)d_in[0];
    const float* W        = (const float*)d_in[1];
    const float* bias     = (const float*)d_in[2];
    const float* eps      = (const float*)d_in[3];
    const float* g1       = (const float*)d_in[4];
    const float* b1       = (const float*)d_in[5];
    const float* g2       = (const float*)d_in[6];
    const float* b2       = (const float*)d_in[7];
    const int*   src      = (const int*)d_in[8];
    const int*   dst      = (const int*)d_in[9];

    const int Nn = in_sizes[0] / DD;   // 100000
    const int E  = in_sizes[8];        // 1600000
    const int L  = 3;
    float* out = (float*)d_out;

    // workspace carve-up
    char* w = (char*)d_ws;
    auto alloc = [&](size_t bytes) -> char* {
        char* p = w;
        w += (bytes + 255) & ~(size_t)255;
        return p;
    };
    int* deg       = (int*)alloc((size_t)Nn * 4);
    int* cursor    = (int*)alloc((size_t)Nn * 4);
    int* row_start = (int*)alloc((size_t)(Nn + 1) * 4);
    int* partials  = (int*)alloc(1024);
    int* pscan     = (int*)alloc(1024);
    int* csr       = (int*)alloc((size_t)E * 4);
    unsigned int* hb = (unsigned int*)alloc((size_t)Nn * 64 * 4);
    unsigned int* zb = (unsigned int*)alloc((size_t)Nn * 64 * 4);
    unsigned short* Wt = (unsigned short*)alloc((size_t)3 * 128 * 128 * 2);
    float* s1sum = (float*)alloc(512);
    float* s1sq  = (float*)alloc(512);
    float* s2sum = (float*)alloc(512);
    float* s2sq  = (float*)alloc(512);
    float* s1    = (float*)alloc(512);
    float* sh1   = (float*)alloc(512);
    float* s2    = (float*)alloc(512);
    float* sh2   = (float*)alloc(512);

    hipMemsetAsync(deg, 0, (size_t)Nn * 4, stream);
    hipMemsetAsync(cursor, 0, (size_t)Nn * 4, stream);
    hipMemsetAsync(s1sum, 0, 4 * 512, stream);  // s1sum,s1sq,s2sum,s2sq contiguous

    const int nb = (Nn + 1023) / 1024;
    k_hist<<<(E + 255) / 256, 256, 0, stream>>>(dst, deg, E);
    k_scan1<<<nb, 1024, 0, stream>>>(deg, partials, Nn);
    k_scan2<<<1, 64, 0, stream>>>(partials, pscan, nb);
    k_scan3<<<nb, 1024, 0, stream>>>(deg, pscan, row_start, Nn, E);
    k_scatter<<<(E + 255) / 256, 256, 0, stream>>>(src, dst, row_start, cursor, csr, E);

    const int total4 = Nn * DD / 4;
    k_cvt_feat<<<(total4 + 255) / 256, 256, 0, stream>>>(features, out, hb, total4);
    k_cvtW<<<(3 * 128 * 128 + 255) / 256, 256, 0, stream>>>(W, Wt, 3 * 128 * 128);

    const float invN = 1.0f / (float)Nn;
    for (int l = 0; l < L; l++) {
        float* y = out + (size_t)(l + 1) * Nn * DD;
        k_gather<<<(Nn + 3) / 4, 256, 0, stream>>>(hb, row_start, csr, eps, l, zb, Nn);
        k_gemm<<<(Nn + 63) / 64, 256, 0, stream>>>((const unsigned short*)zb, Wt, bias, l, y,
                                                   s1sum, s1sq, Nn);
        k_fin<<<1, 128, 0, stream>>>(s1sum, s1sq, g1, b1, l, s1, sh1, invN);
        k_stats2<<<512, 256, 0, stream>>>(y, s1, sh1, s2sum, s2sq, Nn);
        k_fin<<<1, 128, 0, stream>>>(s2sum, s2sq, g2, b2, l, s2, sh2, invN);
        k_apply<<<(total4 + 255) / 256, 256, 0, stream>>>(y, s1, sh1, s2, sh2, hb, total4);
    }
}